// Round 8
// baseline (155.461 us; speedup 1.0000x reference)
//
#include <hip/hip_runtime.h>
#include <hip/hip_bf16.h>
#include <math.h>

#define B_N 8192
#define E_N 512
#define T_N 32
#define BP 520  // B LDS pitch in shorts (1040 B = 65*16: 16B-aligned rows)

typedef short bf16x8 __attribute__((ext_vector_type(8)));
typedef float f32x4 __attribute__((ext_vector_type(4)));

// ---------------- ws layout (bytes) ----------------
#define WS_OFFS   256      // fallback
#define WS_RANK   512      // fallback
#define WS_ORDER  33280    // fallback
#define WS_YACC   66048    // fallback
#define WS_YACC8  98816    // main: 8 x 8192 floats (256 KB), slab = nt
#define WS_REQ    (WS_YACC8 + 8 * B_N * 4)

static __device__ __forceinline__ unsigned short f2bf(float f) {
    unsigned int u = __float_as_uint(f);
    unsigned int r = u + 0x7fffu + ((u >> 16) & 1u);  // RNE
    return (unsigned short)(r >> 16);
}

// packed f32x2 -> bf16x2 (RNE)
static __device__ __forceinline__ unsigned int pk2(float a, float b) {
    __hip_bfloat162 h = __float22bfloat162_rn(float2{a, b});
    unsigned int u;
    __builtin_memcpy(&u, &h, 4);
    return u;
}

// ---------- fused GEMM v6: one block per (tissue, 64-col slice) ----------
// wi = nt*32 + t  =>  wi % 8 == t % 8: all 8 blocks of a tissue on one XCD (L2 A-reuse).
// B (W1 slice) transposed fp32->bf16 into LDS once; K-loop barrier-free:
// A frags straight from global (L2-hot), B frags from LDS.
__global__ __launch_bounds__(512) void k_gemm_mfma(
    const float* __restrict__ g_exp, const float* __restrict__ W1,
    const int* __restrict__ tv, const float* __restrict__ b1,
    const float* __restrict__ W2, float* __restrict__ yacc8) {
    int wi = blockIdx.x;
    int t = wi & 31, nt = wi >> 5;
    int n0 = nt * 64;

    int tid = threadIdx.x;
    int w = tid >> 6, lane = tid & 63;
    int quad = (lane >> 4) & 3, l15 = lane & 15;

    __shared__ __align__(16) unsigned short Bs[64 * BP];  // 66560 B
    __shared__ int rows_s[512];
    __shared__ int wsum[8];

    // per-lane epilogue constants (cols n0 + ni*16 + l15)
    float b1v[4], w2v[4];
#pragma unroll
    for (int ni = 0; ni < 4; ++ni) {
        int n = t * E_N + n0 + ni * 16 + l15;
        b1v[ni] = b1[n];
        w2v[ni] = W2[n];
    }

    // ---- counting-sort slice for tissue t (512 thr x 16 items) ----
    int tvals[16];
    const int4* tvp = (const int4*)(tv + tid * 16);
#pragma unroll
    for (int j = 0; j < 4; ++j) ((int4*)tvals)[j] = tvp[j];
    int myc = 0;
#pragma unroll
    for (int j = 0; j < 16; ++j) myc += (tvals[j] == t) ? 1 : 0;
    int inc = myc;
#pragma unroll
    for (int o = 1; o < 64; o <<= 1) {
        int u = __shfl_up(inc, o, 64);
        if (lane >= o) inc += u;
    }
    if (lane == 63) wsum[w] = inc;
    rows_s[tid] = 0;
    __syncthreads();
    int n_t = 0, wbase = 0;
#pragma unroll
    for (int i = 0; i < 8; ++i) {
        int v = wsum[i];
        n_t += v;
        if (i < w) wbase += v;
    }
    int nt_c = n_t > 512 ? 512 : n_t;
    int rk = wbase + inc - myc;
#pragma unroll
    for (int j = 0; j < 16; ++j)
        if (tvals[j] == t) {
            int rr = rk++;
            if (rr < 512) rows_s[rr] = tid * 16 + j;
        }

    // ---- B prologue: W1[t][k][n0:n0+64] fp32 -> Bs[n][k] bf16 (k-major, packed pairs) ----
    const float* Wsrc = W1 + (size_t)t * E_N * E_N + n0;
    unsigned int* Bw = (unsigned int*)Bs;  // word idx = n*260 + k2 (k = 2*k2)
#pragma unroll
    for (int i = 0; i < 8; ++i) {
        int flat = i * 512 + tid;  // 0..4095
        int k2 = flat >> 4, nq = flat & 15;
        float4 va = *(const float4*)(Wsrc + (size_t)(2 * k2) * E_N + nq * 4);
        float4 vb = *(const float4*)(Wsrc + (size_t)(2 * k2 + 1) * E_N + nq * 4);
        Bw[(nq * 4 + 0) * 260 + k2] = pk2(va.x, vb.x);
        Bw[(nq * 4 + 1) * 260 + k2] = pk2(va.y, vb.y);
        Bw[(nq * 4 + 2) * 260 + k2] = pk2(va.z, vb.z);
        Bw[(nq * 4 + 3) * 260 + k2] = pk2(va.w, vb.w);
    }
    __syncthreads();  // the ONLY barrier before the K-loop

    // ---- m-chunk loop: 128 rows/chunk, wave w owns rows w*16..w*16+15 ----
    int MC = (nt_c + 127) >> 7;
    for (int mc = 0; mc < MC; ++mc) {
        int arow = rows_s[mc * 128 + w * 16 + l15];
        const float* ap = g_exp + (size_t)arow * E_N + quad * 8;

        f32x4 acc[4];
#pragma unroll
        for (int ni = 0; ni < 4; ++ni) acc[ni] = (f32x4){0.f, 0.f, 0.f, 0.f};

#pragma unroll
        for (int it = 0; it < 16; ++it) {
            int k0 = it * 32;
            f32x4 a0 = *(const f32x4*)(ap + k0);
            f32x4 a1 = *(const f32x4*)(ap + k0 + 4);
            unsigned int uu[4] = {pk2(a0[0], a0[1]), pk2(a0[2], a0[3]),
                                  pk2(a1[0], a1[1]), pk2(a1[2], a1[3])};
            bf16x8 af;
            __builtin_memcpy(&af, uu, 16);
#pragma unroll
            for (int ni = 0; ni < 4; ++ni) {
                bf16x8 bfr = *(const bf16x8*)(Bs + (ni * 16 + l15) * BP + k0 + quad * 8);
                acc[ni] = __builtin_amdgcn_mfma_f32_16x16x32_bf16(af, bfr, acc[ni], 0, 0, 0);
            }
        }

        // epilogue: gelu(acc + b1) * W2, dot over this block's 64 cols
        float pr[4] = {0.f, 0.f, 0.f, 0.f};
#pragma unroll
        for (int ni = 0; ni < 4; ++ni) {
#pragma unroll
            for (int r = 0; r < 4; ++r) {
                float u = acc[ni][r] + b1v[ni];
                float gg = 0.5f * u * (1.f + erff(u * 0.70710678118654752f));
                pr[r] = fmaf(gg, w2v[ni], pr[r]);
            }
        }
#pragma unroll
        for (int off = 1; off <= 8; off <<= 1)
#pragma unroll
            for (int r = 0; r < 4; ++r) pr[r] += __shfl_xor(pr[r], off, 64);

        if (l15 == 0) {
            float* slab = yacc8 + (size_t)nt * B_N;
#pragma unroll
            for (int r = 0; r < 4; ++r) {
                int rr = mc * 128 + w * 16 + quad * 4 + r;
                if (rr < nt_c) slab[rows_s[rr]] = pr[r];
            }
        }
    }
}

__global__ void k_final8(const float* __restrict__ yacc8, const int* __restrict__ tv,
                         const float* __restrict__ b2, float* __restrict__ out) {
    int b = blockIdx.x * blockDim.x + threadIdx.x;
    if (b < B_N) {
        float x = b2[tv[b]];
#pragma unroll
        for (int s = 0; s < 8; ++s) x += yacc8[(size_t)s * B_N + b];
        out[b] = fmaxf(x, 0.f) + log1pf(expf(-fabsf(x)));  // stable softplus
    }
}

// ================= fallback (fp32 path, proven) =================
__global__ __launch_bounds__(256) void k_prep_sb(
    const int* __restrict__ tv, int* __restrict__ offs_g,
    int* __restrict__ rank, int* __restrict__ order, float* __restrict__ yacc) {
    __shared__ int lh[4][32], wcur[4][32], offs_s[33];
    int tid = threadIdx.x, w = tid >> 6;
    if (tid < 128) lh[tid >> 5][tid & 31] = 0;
    __syncthreads();
    int tval[32];
#pragma unroll
    for (int c = 0; c < 32; ++c) tval[c] = tv[c * 256 + tid];
#pragma unroll
    for (int c = 0; c < 32; ++c) atomicAdd(&lh[w][tval[c]], 1);
    __syncthreads();
    if (tid < 32) {
        int s = lh[0][tid] + lh[1][tid] + lh[2][tid] + lh[3][tid];
        int excl = 0;
#pragma unroll
        for (int i = 0; i < 32; ++i) {
            int v = __shfl(s, i, 64);
            if (i < tid) excl += v;
        }
        offs_s[tid] = excl;
        offs_g[tid] = excl;
        if (tid == 31) { offs_s[32] = excl + s; offs_g[32] = excl + s; }
    }
    __syncthreads();
    if (tid < 128) {
        int ww = tid >> 5, t = tid & 31;
        int s = offs_s[t];
        for (int w2 = 0; w2 < ww; ++w2) s += lh[w2][t];
        wcur[ww][t] = s;
    }
    __syncthreads();
#pragma unroll
    for (int c = 0; c < 32; ++c) {
        int b = c * 256 + tid;
        int pos = atomicAdd(&wcur[w][tval[c]], 1);
        rank[b] = pos;
        order[pos] = b;
    }
    float4 z = make_float4(0.f, 0.f, 0.f, 0.f);
#pragma unroll
    for (int c = 0; c < 8; ++c) *(float4*)(yacc + (c * 256 + tid) * 4) = z;
}

__global__ __launch_bounds__(256) void fb_gemm(
    const float* __restrict__ g_exp, const float* __restrict__ W1,
    const float* __restrict__ b1, const float* __restrict__ W2,
    const int* __restrict__ offs, const int* __restrict__ order,
    float* __restrict__ yacc) {
    int t = blockIdx.z;
    int base = offs[t];
    int n_t = offs[t + 1] - base;
    int m0 = blockIdx.y * 64;
    if (m0 >= n_t) return;
    int n0 = blockIdx.x * 128;

    __shared__ float As[32][68];
    __shared__ float Bs2[32][128];
    __shared__ int sidx[64];

    int tid = threadIdx.x;
    if (tid < 64) {
        int m = m0 + tid;
        sidx[tid] = (m < n_t) ? order[base + m] : -1;
    }
    __syncthreads();

    int ty = tid >> 4, tx = tid & 15;
    float acc[4][8];
#pragma unroll
    for (int r = 0; r < 4; ++r)
#pragma unroll
        for (int c = 0; c < 8; ++c) acc[r][c] = 0.f;

    for (int k0 = 0; k0 < E_N; k0 += 32) {
#pragma unroll
        for (int p = 0; p < 2; ++p) {
            int idx = tid + 256 * p;
            int row = idx >> 3, kcq = idx & 7;
            int s = sidx[row];
            float4 v = make_float4(0.f, 0.f, 0.f, 0.f);
            if (s >= 0) v = *(const float4*)(g_exp + (size_t)s * E_N + k0 + kcq * 4);
            As[kcq * 4 + 0][row] = v.x;
            As[kcq * 4 + 1][row] = v.y;
            As[kcq * 4 + 2][row] = v.z;
            As[kcq * 4 + 3][row] = v.w;
        }
#pragma unroll
        for (int p = 0; p < 4; ++p) {
            int idx = tid + 256 * p;
            int kr = idx >> 5, c4 = idx & 31;
            *(float4*)(&Bs2[kr][c4 * 4]) =
                *(const float4*)(W1 + ((size_t)t * E_N + (k0 + kr)) * E_N + n0 + c4 * 4);
        }
        __syncthreads();
#pragma unroll
        for (int e = 0; e < 32; ++e) {
            float4 a = *(const float4*)(&As[e][ty * 4]);
            float4 bA = *(const float4*)(&Bs2[e][tx * 4]);
            float4 bB = *(const float4*)(&Bs2[e][tx * 4 + 64]);
            float av[4] = {a.x, a.y, a.z, a.w};
            float bv[8] = {bA.x, bA.y, bA.z, bA.w, bB.x, bB.y, bB.z, bB.w};
#pragma unroll
            for (int r = 0; r < 4; ++r)
#pragma unroll
                for (int c = 0; c < 8; ++c) acc[r][c] = fmaf(av[r], bv[c], acc[r][c]);
        }
        __syncthreads();
    }

    float pr[4] = {0.f, 0.f, 0.f, 0.f};
#pragma unroll
    for (int c = 0; c < 8; ++c) {
        int n = n0 + tx * 4 + ((c >= 4) ? 64 : 0) + (c & 3);
        float bb = b1[t * E_N + n];
        float w2 = W2[t * E_N + n];
#pragma unroll
        for (int r = 0; r < 4; ++r) {
            float u = acc[r][c] + bb;
            float g = 0.5f * u * (1.f + erff(u * 0.70710678118654752f));
            pr[r] = fmaf(g, w2, pr[r]);
        }
    }
#pragma unroll
    for (int off = 8; off >= 1; off >>= 1)
#pragma unroll
        for (int r = 0; r < 4; ++r) pr[r] += __shfl_xor(pr[r], off, 64);

    if (tx == 0) {
#pragma unroll
        for (int r = 0; r < 4; ++r) {
            int m = m0 + ty * 4 + r;
            if (m < n_t) atomicAdd(&yacc[sidx[ty * 4 + r]], pr[r]);
        }
    }
}

__global__ void fb_final(const float* __restrict__ yacc, const int* __restrict__ tv,
                         const float* __restrict__ b2, float* __restrict__ out) {
    int b = blockIdx.x * blockDim.x + threadIdx.x;
    if (b < B_N) {
        float x = yacc[b] + b2[tv[b]];
        out[b] = fmaxf(x, 0.f) + log1pf(expf(-fabsf(x)));
    }
}

extern "C" void kernel_launch(void* const* d_in, const int* in_sizes, int n_in,
                              void* d_out, int out_size, void* d_ws, size_t ws_size,
                              hipStream_t stream) {
    const float* g_exp = (const float*)d_in[0];
    const int*   tv    = (const int*)d_in[1];
    const float* W1    = (const float*)d_in[2];
    const float* b1    = (const float*)d_in[3];
    const float* W2    = (const float*)d_in[4];
    const float* b2    = (const float*)d_in[5];
    float* out = (float*)d_out;

    char* ws = (char*)d_ws;

    if (ws_size >= (size_t)WS_REQ) {
        float* yacc8 = (float*)(ws + WS_YACC8);
        k_gemm_mfma<<<256, 512, 0, stream>>>(g_exp, W1, tv, b1, W2, yacc8);
        k_final8<<<32, 256, 0, stream>>>(yacc8, tv, b2, out);
    } else {
        int* offs   = (int*)(ws + WS_OFFS);
        int* rank   = (int*)(ws + WS_RANK);
        int* order  = (int*)(ws + WS_ORDER);
        float* yacc = (float*)(ws + WS_YACC);
        k_prep_sb<<<1, 256, 0, stream>>>(tv, offs, rank, order, yacc);
        fb_gemm<<<dim3(4, 8, 32), 256, 0, stream>>>(g_exp, W1, b1, W2, offs, order, yacc);
        fb_final<<<32, 256, 0, stream>>>(yacc, tv, b2, out);
    }
}

// Round 9
// 112.049 us; speedup vs baseline: 1.3874x; 1.3874x over previous
//
#include <hip/hip_runtime.h>
#include <hip/hip_bf16.h>
#include <math.h>

#define B_N 8192
#define E_N 512
#define T_N 32
#define BP 520  // B LDS pitch in shorts (1040 B, 16B-aligned rows)

typedef short bf16x8 __attribute__((ext_vector_type(8)));
typedef float f32x4 __attribute__((ext_vector_type(4)));

// ---------------- ws layout (bytes) ----------------
#define WS_OFFS   256      // fallback
#define WS_RANK   512      // fallback
#define WS_ORDER  33280    // fallback
#define WS_YACC   66048    // fallback
#define WS_YACC8  98816    // main: 8 x 8192 floats (256 KB), slab = nt
#define WS_REQ    (WS_YACC8 + 8 * B_N * 4)

typedef __attribute__((address_space(1))) const unsigned int gas_u32;
typedef __attribute__((address_space(3))) unsigned int las_u32;

static __device__ __forceinline__ unsigned short f2bf(float f) {
    unsigned int u = __float_as_uint(f);
    unsigned int r = u + 0x7fffu + ((u >> 16) & 1u);  // RNE
    return (unsigned short)(r >> 16);
}

// packed f32x2 -> bf16x2 (RNE)
static __device__ __forceinline__ unsigned int pk2(float a, float b) {
    __hip_bfloat162 h = __float22bfloat162_rn(float2{a, b});
    unsigned int u;
    __builtin_memcpy(&u, &h, 4);
    return u;
}

// ---------- fused GEMM v7: (tissue, 64-col slice) blocks; B LDS-resident;
// A fp32 via DMA pipeline (depth 3, raw s_barrier + vmcnt(2)) ----------
// wi = nt*32 + t  =>  wi % 8 == t % 8: all 8 blocks of a tissue on one XCD (L2 A-reuse).
__global__ __launch_bounds__(512, 1) void k_gemm_mfma(
    const float* __restrict__ g_exp, const float* __restrict__ W1,
    const int* __restrict__ tv, const float* __restrict__ b1,
    const float* __restrict__ W2, float* __restrict__ yacc8) {
    int wi = blockIdx.x;
    int t = wi & 31, nt = wi >> 5;
    int n0 = nt * 64;

    int tid = threadIdx.x;
    int w = tid >> 6, lane = tid & 63;
    int quad = (lane >> 4) & 3, l15 = lane & 15;

    __shared__ __align__(16) unsigned short Bs[64 * BP];  // 66560 B, resident all kernel
    __shared__ __align__(16) float As[3][128 * 32];       // 48 KB, A pipeline
    __shared__ int rows_s[512];
    __shared__ int wsum[8];

    // per-lane epilogue constants (cols n0 + ni*16 + l15)
    float b1v[4], w2v[4];
#pragma unroll
    for (int ni = 0; ni < 4; ++ni) {
        int n = t * E_N + n0 + ni * 16 + l15;
        b1v[ni] = b1[n];
        w2v[ni] = W2[n];
    }

    // ---- counting-sort slice for tissue t (512 thr x 16 items) ----
    int tvals[16];
    const int4* tvp = (const int4*)(tv + tid * 16);
#pragma unroll
    for (int j = 0; j < 4; ++j) ((int4*)tvals)[j] = tvp[j];
    int myc = 0;
#pragma unroll
    for (int j = 0; j < 16; ++j) myc += (tvals[j] == t) ? 1 : 0;
    int inc = myc;
#pragma unroll
    for (int o = 1; o < 64; o <<= 1) {
        int u = __shfl_up(inc, o, 64);
        if (lane >= o) inc += u;
    }
    if (lane == 63) wsum[w] = inc;
    rows_s[tid] = 0;
    __syncthreads();
    int n_t = 0, wbase = 0;
#pragma unroll
    for (int i = 0; i < 8; ++i) {
        int v = wsum[i];
        n_t += v;
        if (i < w) wbase += v;
    }
    int nt_c = n_t > 512 ? 512 : n_t;
    int rk = wbase + inc - myc;
#pragma unroll
    for (int j = 0; j < 16; ++j)
        if (tvals[j] == t) {
            int rr = rk++;
            if (rr < 512) rows_s[rr] = tid * 16 + j;
        }

    // ---- B prologue: W1[t][k][n0:n0+64] fp32 -> Bs[n][k] bf16 (k-major, packed pairs) ----
    const float* Wsrc = W1 + (size_t)t * E_N * E_N + n0;
    unsigned int* Bw = (unsigned int*)Bs;  // word idx = n*260 + k2 (k = 2*k2)
#pragma unroll
    for (int i = 0; i < 8; ++i) {
        int flat = i * 512 + tid;  // 0..4095
        int k2 = flat >> 4, nq = flat & 15;
        float4 va = *(const float4*)(Wsrc + (size_t)(2 * k2) * E_N + nq * 4);
        float4 vb = *(const float4*)(Wsrc + (size_t)(2 * k2 + 1) * E_N + nq * 4);
        Bw[(nq * 4 + 0) * 260 + k2] = pk2(va.x, vb.x);
        Bw[(nq * 4 + 1) * 260 + k2] = pk2(va.y, vb.y);
        Bw[(nq * 4 + 2) * 260 + k2] = pk2(va.z, vb.z);
        Bw[(nq * 4 + 3) * 260 + k2] = pk2(va.w, vb.w);
    }
    __syncthreads();  // rows_s + Bs final

    // ---- A DMA mapping: tile = 128 rows x 32 k fp32 = 1024 x 16B chunks.
    // chunk d: row = d>>3, kc = (d&7)^(row&7) (XOR swizzle; frag reads conflict-free).
    int d0 = tid, d1 = tid + 512;
    int ar0 = d0 >> 3, ac0 = (d0 & 7) ^ (ar0 & 7);
    int ar1 = d1 >> 3, ac1 = (d1 & 7) ^ (ar1 & 7);

    int lrow = w * 16 + l15;                 // A-frag row within 128-chunk
    int c0 = (quad * 2) ^ (lrow & 7);        // frag LDS chunk (lo 16B)
    int c1 = (quad * 2 + 1) ^ (lrow & 7);    // frag LDS chunk (hi 16B)

    float* slab = yacc8 + (size_t)nt * B_N;

    int MC = (nt_c + 127) >> 7;
    for (int mc = 0; mc < MC; ++mc) {
        const float* pA0 = g_exp + (size_t)rows_s[mc * 128 + ar0] * E_N + ac0 * 4;
        const float* pA1 = g_exp + (size_t)rows_s[mc * 128 + ar1] * E_N + ac1 * 4;

#define ISSUE(kk) do {                                                                      \
        __builtin_amdgcn_global_load_lds((gas_u32*)(pA0 + (kk) * 32),                       \
                                         (las_u32*)&As[(kk) % 3][d0 * 4], 16, 0, 0);        \
        __builtin_amdgcn_global_load_lds((gas_u32*)(pA1 + (kk) * 32),                       \
                                         (las_u32*)&As[(kk) % 3][d1 * 4], 16, 0, 0);        \
    } while (0)

        ISSUE(0);
        ISSUE(1);

        f32x4 acc[4];
#pragma unroll
        for (int ni = 0; ni < 4; ++ni) acc[ni] = (f32x4){0.f, 0.f, 0.f, 0.f};

        // Stage it: vmcnt(2) -> tile it landed (only tile it+1's 2 DMAs remain);
        // raw s_barrier (no compiler vmcnt(0) drain); compute; refill buf (it+2)%3.
#define STAGE(it, W) do {                                                                   \
        asm volatile("s_waitcnt vmcnt(%0)" :: "n"(W) : "memory");                           \
        asm volatile("s_barrier" ::: "memory");                                             \
        const float* Ab = &As[(it) % 3][0];                                                 \
        f32x4 lo = *(const f32x4*)(Ab + (lrow * 8 + c0) * 4);                               \
        f32x4 hi = *(const f32x4*)(Ab + (lrow * 8 + c1) * 4);                               \
        unsigned int uu[4] = {pk2(lo[0], lo[1]), pk2(lo[2], lo[3]),                         \
                              pk2(hi[0], hi[1]), pk2(hi[2], hi[3])};                        \
        bf16x8 af;                                                                          \
        __builtin_memcpy(&af, uu, 16);                                                      \
        _Pragma("unroll") for (int ni = 0; ni < 4; ++ni) {                                  \
            bf16x8 bfr = *(const bf16x8*)(Bs + (ni * 16 + l15) * BP + (it) * 32 + quad * 8);\
            acc[ni] = __builtin_amdgcn_mfma_f32_16x16x32_bf16(af, bfr, acc[ni], 0, 0, 0);   \
        }                                                                                   \
        if ((it) + 2 < 16) ISSUE((it) + 2);                                                 \
    } while (0)

        STAGE(0, 2);  STAGE(1, 2);  STAGE(2, 2);  STAGE(3, 2);
        STAGE(4, 2);  STAGE(5, 2);  STAGE(6, 2);  STAGE(7, 2);
        STAGE(8, 2);  STAGE(9, 2);  STAGE(10, 2); STAGE(11, 2);
        STAGE(12, 2); STAGE(13, 2); STAGE(14, 2); STAGE(15, 0);
#undef STAGE
#undef ISSUE

        // epilogue: gelu(acc + b1) * W2, dot over this block's 64 cols
        float pr[4] = {0.f, 0.f, 0.f, 0.f};
#pragma unroll
        for (int ni = 0; ni < 4; ++ni) {
#pragma unroll
            for (int r = 0; r < 4; ++r) {
                float u = acc[ni][r] + b1v[ni];
                float gg = 0.5f * u * (1.f + erff(u * 0.70710678118654752f));
                pr[r] = fmaf(gg, w2v[ni], pr[r]);
            }
        }
#pragma unroll
        for (int off = 1; off <= 8; off <<= 1)
#pragma unroll
            for (int r = 0; r < 4; ++r) pr[r] += __shfl_xor(pr[r], off, 64);

        if (l15 == 0) {
#pragma unroll
            for (int r = 0; r < 4; ++r) {
                int rr = mc * 128 + w * 16 + quad * 4 + r;
                if (rr < nt_c) slab[rows_s[rr]] = pr[r];
            }
        }
    }
}

__global__ void k_final8(const float* __restrict__ yacc8, const int* __restrict__ tv,
                         const float* __restrict__ b2, float* __restrict__ out) {
    int b = blockIdx.x * blockDim.x + threadIdx.x;
    if (b < B_N) {
        float x = b2[tv[b]];
#pragma unroll
        for (int s = 0; s < 8; ++s) x += yacc8[(size_t)s * B_N + b];
        out[b] = fmaxf(x, 0.f) + log1pf(expf(-fabsf(x)));  // stable softplus
    }
}

// ================= fallback (fp32 path, proven) =================
__global__ __launch_bounds__(256) void k_prep_sb(
    const int* __restrict__ tv, int* __restrict__ offs_g,
    int* __restrict__ rank, int* __restrict__ order, float* __restrict__ yacc) {
    __shared__ int lh[4][32], wcur[4][32], offs_s[33];
    int tid = threadIdx.x, w = tid >> 6;
    if (tid < 128) lh[tid >> 5][tid & 31] = 0;
    __syncthreads();
    int tval[32];
#pragma unroll
    for (int c = 0; c < 32; ++c) tval[c] = tv[c * 256 + tid];
#pragma unroll
    for (int c = 0; c < 32; ++c) atomicAdd(&lh[w][tval[c]], 1);
    __syncthreads();
    if (tid < 32) {
        int s = lh[0][tid] + lh[1][tid] + lh[2][tid] + lh[3][tid];
        int excl = 0;
#pragma unroll
        for (int i = 0; i < 32; ++i) {
            int v = __shfl(s, i, 64);
            if (i < tid) excl += v;
        }
        offs_s[tid] = excl;
        offs_g[tid] = excl;
        if (tid == 31) { offs_s[32] = excl + s; offs_g[32] = excl + s; }
    }
    __syncthreads();
    if (tid < 128) {
        int ww = tid >> 5, t = tid & 31;
        int s = offs_s[t];
        for (int w2 = 0; w2 < ww; ++w2) s += lh[w2][t];
        wcur[ww][t] = s;
    }
    __syncthreads();
#pragma unroll
    for (int c = 0; c < 32; ++c) {
        int b = c * 256 + tid;
        int pos = atomicAdd(&wcur[w][tval[c]], 1);
        rank[b] = pos;
        order[pos] = b;
    }
    float4 z = make_float4(0.f, 0.f, 0.f, 0.f);
#pragma unroll
    for (int c = 0; c < 8; ++c) *(float4*)(yacc + (c * 256 + tid) * 4) = z;
}

__global__ __launch_bounds__(256) void fb_gemm(
    const float* __restrict__ g_exp, const float* __restrict__ W1,
    const float* __restrict__ b1, const float* __restrict__ W2,
    const int* __restrict__ offs, const int* __restrict__ order,
    float* __restrict__ yacc) {
    int t = blockIdx.z;
    int base = offs[t];
    int n_t = offs[t + 1] - base;
    int m0 = blockIdx.y * 64;
    if (m0 >= n_t) return;
    int n0 = blockIdx.x * 128;

    __shared__ float As2[32][68];
    __shared__ float Bs2[32][128];
    __shared__ int sidx[64];

    int tid = threadIdx.x;
    if (tid < 64) {
        int m = m0 + tid;
        sidx[tid] = (m < n_t) ? order[base + m] : -1;
    }
    __syncthreads();

    int ty = tid >> 4, tx = tid & 15;
    float acc[4][8];
#pragma unroll
    for (int r = 0; r < 4; ++r)
#pragma unroll
        for (int c = 0; c < 8; ++c) acc[r][c] = 0.f;

    for (int k0 = 0; k0 < E_N; k0 += 32) {
#pragma unroll
        for (int p = 0; p < 2; ++p) {
            int idx = tid + 256 * p;
            int row = idx >> 3, kcq = idx & 7;
            int s = sidx[row];
            float4 v = make_float4(0.f, 0.f, 0.f, 0.f);
            if (s >= 0) v = *(const float4*)(g_exp + (size_t)s * E_N + k0 + kcq * 4);
            As2[kcq * 4 + 0][row] = v.x;
            As2[kcq * 4 + 1][row] = v.y;
            As2[kcq * 4 + 2][row] = v.z;
            As2[kcq * 4 + 3][row] = v.w;
        }
#pragma unroll
        for (int p = 0; p < 4; ++p) {
            int idx = tid + 256 * p;
            int kr = idx >> 5, c4 = idx & 31;
            *(float4*)(&Bs2[kr][c4 * 4]) =
                *(const float4*)(W1 + ((size_t)t * E_N + (k0 + kr)) * E_N + n0 + c4 * 4);
        }
        __syncthreads();
#pragma unroll
        for (int e = 0; e < 32; ++e) {
            float4 a = *(const float4*)(&As2[e][ty * 4]);
            float4 bA = *(const float4*)(&Bs2[e][tx * 4]);
            float4 bB = *(const float4*)(&Bs2[e][tx * 4 + 64]);
            float av[4] = {a.x, a.y, a.z, a.w};
            float bv[8] = {bA.x, bA.y, bA.z, bA.w, bB.x, bB.y, bB.z, bB.w};
#pragma unroll
            for (int r = 0; r < 4; ++r)
#pragma unroll
                for (int c = 0; c < 8; ++c) acc[r][c] = fmaf(av[r], bv[c], acc[r][c]);
        }
        __syncthreads();
    }

    float pr[4] = {0.f, 0.f, 0.f, 0.f};
#pragma unroll
    for (int c = 0; c < 8; ++c) {
        int n = n0 + tx * 4 + ((c >= 4) ? 64 : 0) + (c & 3);
        float bb = b1[t * E_N + n];
        float w2 = W2[t * E_N + n];
#pragma unroll
        for (int r = 0; r < 4; ++r) {
            float u = acc[r][c] + bb;
            float g = 0.5f * u * (1.f + erff(u * 0.70710678118654752f));
            pr[r] = fmaf(g, w2, pr[r]);
        }
    }
#pragma unroll
    for (int off = 8; off >= 1; off >>= 1)
#pragma unroll
        for (int r = 0; r < 4; ++r) pr[r] += __shfl_xor(pr[r], off, 64);

    if (tx == 0) {
#pragma unroll
        for (int r = 0; r < 4; ++r) {
            int m = m0 + ty * 4 + r;
            if (m < n_t) atomicAdd(&yacc[sidx[ty * 4 + r]], pr[r]);
        }
    }
}

__global__ void fb_final(const float* __restrict__ yacc, const int* __restrict__ tv,
                         const float* __restrict__ b2, float* __restrict__ out) {
    int b = blockIdx.x * blockDim.x + threadIdx.x;
    if (b < B_N) {
        float x = yacc[b] + b2[tv[b]];
        out[b] = fmaxf(x, 0.f) + log1pf(expf(-fabsf(x)));
    }
}

extern "C" void kernel_launch(void* const* d_in, const int* in_sizes, int n_in,
                              void* d_out, int out_size, void* d_ws, size_t ws_size,
                              hipStream_t stream) {
    const float* g_exp = (const float*)d_in[0];
    const int*   tv    = (const int*)d_in[1];
    const float* W1    = (const float*)d_in[2];
    const float* b1    = (const float*)d_in[3];
    const float* W2    = (const float*)d_in[4];
    const float* b2    = (const float*)d_in[5];
    float* out = (float*)d_out;

    char* ws = (char*)d_ws;

    if (ws_size >= (size_t)WS_REQ) {
        float* yacc8 = (float*)(ws + WS_YACC8);
        k_gemm_mfma<<<256, 512, 0, stream>>>(g_exp, W1, tv, b1, W2, yacc8);
        k_final8<<<32, 256, 0, stream>>>(yacc8, tv, b2, out);
    } else {
        int* offs   = (int*)(ws + WS_OFFS);
        int* rank   = (int*)(ws + WS_RANK);
        int* order  = (int*)(ws + WS_ORDER);
        float* yacc = (float*)(ws + WS_YACC);
        k_prep_sb<<<1, 256, 0, stream>>>(tv, offs, rank, order, yacc);
        fb_gemm<<<dim3(4, 8, 32), 256, 0, stream>>>(g_exp, W1, b1, W2, offs, order, yacc);
        fb_final<<<32, 256, 0, stream>>>(yacc, tv, b2, out);
    }
}